// Round 2
// baseline (3394.323 us; speedup 1.0000x reference)
//
#include <hip/hip_runtime.h>
#include <hip/hip_bf16.h>
#include <math.h>

#define Bb 16
#define Nn 512
#define Dd 256
#define Hh 8
#define HD 32
#define Ll 3
#define INDIM 768
#define Ee 4096
#define FF 1024

__device__ __forceinline__ float gelu_exact(float x) {
    return 0.5f * x * (1.0f + erff(x * 0.70710678118654752f));
}

// ---------------- edge bucketing ----------------

__global__ __launch_bounds__(256) void zero_kernel(int* __restrict__ p, int n) {
    int gid = blockIdx.x * 256 + threadIdx.x;
    if (gid < n) p[gid] = 0;
}

__global__ __launch_bounds__(256) void count_kernel(const int* __restrict__ edge_index,
                                                    int* __restrict__ counts) {
    int gid = blockIdx.x * 256 + threadIdx.x; // B*E = 65536
    int b = gid >> 12;
    int e = gid & (Ee - 1);
    int src = edge_index[b * 2 * Ee + e];
    atomicAdd(&counts[b * Nn + src], 1);
}

__global__ __launch_bounds__(1024) void scan_kernel(const int* __restrict__ counts,
                                                    int* __restrict__ offsets,
                                                    int* __restrict__ cursor) {
    // one block, 1024 threads, 8192 buckets
    __shared__ int ssum[1024];
    int t = threadIdx.x;
    int local[8];
    int s = 0;
#pragma unroll
    for (int i = 0; i < 8; i++) { local[i] = counts[t * 8 + i]; s += local[i]; }
    ssum[t] = s;
    __syncthreads();
    for (int off = 1; off < 1024; off *= 2) {
        __syncthreads();
        int v = (t >= off) ? ssum[t - off] : 0;
        __syncthreads();
        ssum[t] += v;
    }
    __syncthreads();
    int base = (t > 0) ? ssum[t - 1] : 0;
#pragma unroll
    for (int i = 0; i < 8; i++) {
        offsets[t * 8 + i] = base;
        cursor[t * 8 + i] = base;
        base += local[i];
    }
    if (t == 1023) offsets[8192] = base; // == B*E
}

__global__ __launch_bounds__(256) void scatter_kernel(const int* __restrict__ edge_index,
                                                      int* __restrict__ cursor,
                                                      int* __restrict__ elist) {
    int gid = blockIdx.x * 256 + threadIdx.x; // B*E
    int b = gid >> 12;
    int e = gid & (Ee - 1);
    int src = edge_index[b * 2 * Ee + e];
    int pos = atomicAdd(&cursor[b * Nn + src], 1);
    elist[pos] = gid; // encodes (b,e)
}

// ---------------- generic tiled fp32 GEMM: C = A(MxK) @ W(KxN) + bias, opt GELU ----------------

#define BM 64
#define BN 64
#define BK 16

__global__ __launch_bounds__(256) void gemm_bias(const float* __restrict__ A,
                                                 const float* __restrict__ W,
                                                 const float* __restrict__ bias,
                                                 float* __restrict__ C,
                                                 int M, int K, int N, int act) {
    __shared__ float sA[BK][BM + 1];
    __shared__ float sB[BK][BN + 1];
    int tid = threadIdx.x;
    int col0 = blockIdx.x * BN;
    int row0 = blockIdx.y * BM;
    int tx = tid & 15, ty = tid >> 4;
    float acc[4][4] = {};
    for (int k0 = 0; k0 < K; k0 += BK) {
#pragma unroll
        for (int i = 0; i < 4; i++) {
            int e = tid + i * 256;
            int r = e >> 4, c = e & 15;
            sA[c][r] = A[(size_t)(row0 + r) * K + k0 + c];
        }
#pragma unroll
        for (int i = 0; i < 4; i++) {
            int e = tid + i * 256;
            int r = e >> 6, c = e & 63;
            sB[r][c] = W[(size_t)(k0 + r) * N + col0 + c];
        }
        __syncthreads();
#pragma unroll
        for (int kk = 0; kk < BK; kk++) {
            float a[4], bv[4];
#pragma unroll
            for (int i = 0; i < 4; i++) a[i] = sA[kk][ty * 4 + i];
#pragma unroll
            for (int j = 0; j < 4; j++) bv[j] = sB[kk][tx * 4 + j];
#pragma unroll
            for (int i = 0; i < 4; i++)
#pragma unroll
                for (int j = 0; j < 4; j++) acc[i][j] += a[i] * bv[j];
        }
        __syncthreads();
    }
#pragma unroll
    for (int i = 0; i < 4; i++) {
        int r = row0 + ty * 4 + i;
#pragma unroll
        for (int j = 0; j < 4; j++) {
            int c = col0 + tx * 4 + j;
            float v = acc[i][j] + bias[c];
            if (act == 1) v = gelu_exact(v);
            C[(size_t)r * N + c] = v;
        }
    }
}

// ---------------- attention: one block per (b,h,n) ----------------

__global__ __launch_bounds__(256) void attn_kernel(const float* __restrict__ qkv,
                                                   const int* __restrict__ node_mask,
                                                   const int* __restrict__ offsets,
                                                   const int* __restrict__ elist,
                                                   const int* __restrict__ edge_index,
                                                   const int* __restrict__ edge_type,
                                                   const float* __restrict__ edge_weight,
                                                   const float* __restrict__ et_emb,
                                                   float* __restrict__ outbuf) {
    int bid = blockIdx.x;        // ((b*H + h)*N + n)
    int n = bid & (Nn - 1);
    int bh = bid >> 9;
    int h = bh & (Hh - 1);
    int b = bh >> 3;
    int t = threadIdx.x;

    __shared__ float s[Nn];
    __shared__ float q_s[HD];
    __shared__ float red[4];
    __shared__ float outred[8][HD];

    const float scale = 0.17677669529663687f; // 1/sqrt(32)
    if (t < HD) q_s[t] = qkv[(size_t)(b * Nn + n) * 768 + h * HD + t] * scale;
    __syncthreads();

    // raw scores
    for (int m = t; m < Nn; m += 256) {
        const float* kp = qkv + (size_t)(b * Nn + m) * 768 + 256 + h * HD;
        float acc = 0.0f;
#pragma unroll
        for (int d = 0; d < HD; d++) acc += q_s[d] * kp[d];
        s[m] = acc;
    }
    __syncthreads();

    // replay bias edges for row (b, src=n)
    int bucket = b * Nn + n;
    int beg = offsets[bucket], end = offsets[bucket + 1];
    for (int i = beg + t; i < end; i += 256) {
        int ge = elist[i];
        int e = ge & (Ee - 1);
        int bb = ge >> 12;
        int dst = edge_index[bb * 2 * Ee + Ee + e];
        int ty2 = edge_type[bb * Ee + e];
        float w = edge_weight[bb * Ee + e];
        float val = et_emb[ty2 * Hh + h] + (ty2 == 2 ? w : 0.0f);
        atomicAdd(&s[dst], val);
    }
    __syncthreads();

    // key mask
    for (int m = t; m < Nn; m += 256) {
        if (!node_mask[b * Nn + m]) s[m] = -INFINITY;
    }
    __syncthreads();

    // rowmax
    float mv = fmaxf(s[t], s[t + 256]);
    for (int o = 32; o > 0; o >>= 1) mv = fmaxf(mv, __shfl_down(mv, o));
    if ((t & 63) == 0) red[t >> 6] = mv;
    __syncthreads();
    if (t == 0) red[0] = fmaxf(fmaxf(red[0], red[1]), fmaxf(red[2], red[3]));
    __syncthreads();
    float rowmax = red[0];
    __syncthreads();

    // exp + sum
    float psum = 0.0f;
    for (int m = t; m < Nn; m += 256) {
        float p = expf(s[m] - rowmax);
        s[m] = p;
        psum += p;
    }
    for (int o = 32; o > 0; o >>= 1) psum += __shfl_down(psum, o);
    if ((t & 63) == 0) red[t >> 6] = psum;
    __syncthreads();
    if (t == 0) red[0] = red[0] + red[1] + red[2] + red[3];
    __syncthreads();
    float inv = 1.0f / red[0];

    // out = P @ V
    int d = t & (HD - 1);
    int chunk = t >> 5; // 8 chunks of 64 m
    float acc = 0.0f;
    int m0 = chunk * 64;
    for (int m = m0; m < m0 + 64; m++) {
        acc += s[m] * qkv[(size_t)(b * Nn + m) * 768 + 512 + h * HD + d];
    }
    outred[chunk][d] = acc;
    __syncthreads();
    if (chunk == 0) {
        float o = 0.0f;
#pragma unroll
        for (int c = 0; c < 8; c++) o += outred[c][d];
        outbuf[(size_t)(b * Nn + n) * Dd + h * HD + d] = o * inv;
    }
}

// ---------------- residual + LayerNorm (two-pass), in-place on x ----------------

__global__ __launch_bounds__(256) void ln_kernel(float* __restrict__ x,
                                                 const float* __restrict__ res,
                                                 const float* __restrict__ g,
                                                 const float* __restrict__ bta) {
    int row = blockIdx.x;
    int t = threadIdx.x;
    __shared__ float red[4];
    __shared__ float stats[2];
    size_t idx = (size_t)row * Dd + t;
    float v = x[idx] + res[idx];
    float sm = v;
    for (int o = 32; o > 0; o >>= 1) sm += __shfl_down(sm, o);
    if ((t & 63) == 0) red[t >> 6] = sm;
    __syncthreads();
    if (t == 0) stats[0] = (red[0] + red[1] + red[2] + red[3]) * (1.0f / Dd);
    __syncthreads();
    float mu = stats[0];
    float dv = v - mu;
    float s2 = dv * dv;
    for (int o = 32; o > 0; o >>= 1) s2 += __shfl_down(s2, o);
    if ((t & 63) == 0) red[t >> 6] = s2;
    __syncthreads();
    if (t == 0) stats[1] = 1.0f / sqrtf((red[0] + red[1] + red[2] + red[3]) * (1.0f / Dd) + 1e-5f);
    __syncthreads();
    x[idx] = dv * stats[1] * g[t] + bta[t];
}

// ---------------- head: pools + cosine + 3-layer MLP, one block per batch ----------------

__global__ __launch_bounds__(256) void head_kernel(const float* __restrict__ x,
                                                   const int* __restrict__ text_mask,
                                                   const int* __restrict__ image_mask,
                                                   const int* __restrict__ gidx,
                                                   const float* __restrict__ Wm1,
                                                   const float* __restrict__ bm1,
                                                   const float* __restrict__ Wm2,
                                                   const float* __restrict__ bm2,
                                                   const float* __restrict__ Wm3,
                                                   const float* __restrict__ bm3,
                                                   float* __restrict__ out) {
    int b = blockIdx.x;
    int t = threadIdx.x;
    __shared__ float comb[769];
    __shared__ float h1[512];
    __shared__ float h2[256];
    __shared__ float redc[8];
    __shared__ float redd[12];
    __shared__ float red[4];

    float tp = 0.0f, ip = 0.0f;
    for (int n = 0; n < Nn; n++) {
        float xv = x[(size_t)(b * Nn + n) * Dd + t];
        tp += xv * (float)text_mask[b * Nn + n];
        ip += xv * (float)image_mask[b * Nn + n];
    }
    float c1 = 0.0f, c2 = 0.0f;
    for (int n = t; n < Nn; n += 256) {
        c1 += (float)text_mask[b * Nn + n];
        c2 += (float)image_mask[b * Nn + n];
    }
    for (int o = 32; o > 0; o >>= 1) { c1 += __shfl_down(c1, o); c2 += __shfl_down(c2, o); }
    if ((t & 63) == 0) { redc[t >> 6] = c1; redc[4 + (t >> 6)] = c2; }
    __syncthreads();
    float tc = fmaxf(redc[0] + redc[1] + redc[2] + redc[3], 1.0f);
    float ic = fmaxf(redc[4] + redc[5] + redc[6] + redc[7], 1.0f);
    tp /= tc;
    ip /= ic;

    int gi = gidx[b];
    comb[t] = x[(size_t)(b * Nn + gi) * Dd + t];
    comb[256 + t] = tp;
    comb[512 + t] = ip;

    float dotv = tp * ip, n1v = tp * tp, n2v = ip * ip;
    for (int o = 32; o > 0; o >>= 1) {
        dotv += __shfl_down(dotv, o);
        n1v += __shfl_down(n1v, o);
        n2v += __shfl_down(n2v, o);
    }
    if ((t & 63) == 0) { redd[t >> 6] = dotv; redd[4 + (t >> 6)] = n1v; redd[8 + (t >> 6)] = n2v; }
    __syncthreads();
    if (t == 0) {
        float dd = redd[0] + redd[1] + redd[2] + redd[3];
        float a1 = fmaxf(sqrtf(redd[4] + redd[5] + redd[6] + redd[7]), 1e-6f);
        float a2 = fmaxf(sqrtf(redd[8] + redd[9] + redd[10] + redd[11]), 1e-6f);
        comb[768] = 1.0f - dd / (a1 * a2);
    }
    __syncthreads();

#pragma unroll
    for (int jj = 0; jj < 2; jj++) {
        int j = t + jj * 256;
        float acc = bm1[j];
        for (int k = 0; k < 769; k++) acc += comb[k] * Wm1[k * 512 + j];
        h1[j] = gelu_exact(acc);
    }
    __syncthreads();
    {
        float acc = bm2[t];
        for (int k = 0; k < 512; k++) acc += h1[k] * Wm2[k * 256 + t];
        h2[t] = gelu_exact(acc);
    }
    __syncthreads();
    float lv = h2[t] * Wm3[t];
    for (int o = 32; o > 0; o >>= 1) lv += __shfl_down(lv, o);
    if ((t & 63) == 0) red[t >> 6] = lv;
    __syncthreads();
    if (t == 0) out[b] = red[0] + red[1] + red[2] + red[3] + bm3[0];
}

// ---------------- launch ----------------

extern "C" void kernel_launch(void* const* d_in, const int* in_sizes, int n_in,
                              void* d_out, int out_size, void* d_ws, size_t ws_size,
                              hipStream_t stream) {
    const float* node_feats = (const float*)d_in[0];
    const int* node_mask = (const int*)d_in[1];
    const int* text_mask = (const int*)d_in[2];
    const int* image_mask = (const int*)d_in[3];
    const int* gidx = (const int*)d_in[4];
    const int* edge_index = (const int*)d_in[5];
    const int* edge_type = (const int*)d_in[6];
    const float* edge_weight = (const float*)d_in[7];
    const float* W_in = (const float*)d_in[8];
    const float* b_in = (const float*)d_in[9];
    const float* Wqkv = (const float*)d_in[10];
    const float* bqkv = (const float*)d_in[11];
    const float* Wo = (const float*)d_in[12];
    const float* bo = (const float*)d_in[13];
    const float* ln1_g = (const float*)d_in[14];
    const float* ln1_b = (const float*)d_in[15];
    const float* ln2_g = (const float*)d_in[16];
    const float* ln2_b = (const float*)d_in[17];
    const float* Wff1 = (const float*)d_in[18];
    const float* bff1 = (const float*)d_in[19];
    const float* Wff2 = (const float*)d_in[20];
    const float* bff2 = (const float*)d_in[21];
    const float* et_emb = (const float*)d_in[22];
    const float* Wm1 = (const float*)d_in[23];
    const float* bm1 = (const float*)d_in[24];
    const float* Wm2 = (const float*)d_in[25];
    const float* bm2 = (const float*)d_in[26];
    const float* Wm3 = (const float*)d_in[27];
    const float* bm3 = (const float*)d_in[28];

    const int M = Bb * Nn; // 8192
    char* ws = (char*)d_ws;
    size_t off = 0;
    auto alloc = [&](size_t bytes) {
        void* p = ws + off;
        off += (bytes + 255) & ~(size_t)255;
        return p;
    };
    // Workspace layout (~56.3 MB): qkvb/ffb share one union buffer (lifetimes
    // disjoint: qkvb dead after attn_kernel, ffb born after ln1).
    float* x = (float*)alloc((size_t)M * Dd * 4);          // 8 MB
    float* qkvb = (float*)alloc((size_t)M * FF * 4);       // 32 MB (union: qkv 24MB / ff 32MB)
    float* ffb = qkvb;
    float* attnout = (float*)alloc((size_t)M * Dd * 4);    // 8 MB
    float* projb = (float*)alloc((size_t)M * Dd * 4);      // 8 MB
    int* counts = (int*)alloc(8192 * 4);
    int* offsets = (int*)alloc(8193 * 4);
    int* cursor = (int*)alloc(8192 * 4);
    int* elist = (int*)alloc((size_t)Bb * Ee * 4);
    (void)ws_size;

    // edge buckets
    zero_kernel<<<32, 256, 0, stream>>>(counts, 8192);
    count_kernel<<<256, 256, 0, stream>>>(edge_index, counts);
    scan_kernel<<<1, 1024, 0, stream>>>(counts, offsets, cursor);
    scatter_kernel<<<256, 256, 0, stream>>>(edge_index, cursor, elist);

    // input projection: x = node_feats @ W_in + b_in
    gemm_bias<<<dim3(Dd / BN, M / BM), 256, 0, stream>>>(node_feats, W_in, b_in, x, M, INDIM, Dd, 0);

    for (int l = 0; l < Ll; l++) {
        gemm_bias<<<dim3(768 / BN, M / BM), 256, 0, stream>>>(
            x, Wqkv + (size_t)l * Dd * 768, bqkv + l * 768, qkvb, M, Dd, 768, 0);
        attn_kernel<<<Bb * Hh * Nn, 256, 0, stream>>>(
            qkvb, node_mask, offsets, elist, edge_index, edge_type, edge_weight, et_emb, attnout);
        gemm_bias<<<dim3(Dd / BN, M / BM), 256, 0, stream>>>(
            attnout, Wo + (size_t)l * Dd * Dd, bo + l * Dd, projb, M, Dd, Dd, 0);
        ln_kernel<<<M, 256, 0, stream>>>(x, projb, ln1_g + l * Dd, ln1_b + l * Dd);
        gemm_bias<<<dim3(FF / BN, M / BM), 256, 0, stream>>>(
            x, Wff1 + (size_t)l * Dd * FF, bff1 + l * FF, ffb, M, Dd, FF, 1);
        gemm_bias<<<dim3(Dd / BN, M / BM), 256, 0, stream>>>(
            ffb, Wff2 + (size_t)l * FF * Dd, bff2 + l * Dd, projb, M, FF, Dd, 0);
        ln_kernel<<<M, 256, 0, stream>>>(x, projb, ln2_g + l * Dd, ln2_b + l * Dd);
    }

    head_kernel<<<Bb, 256, 0, stream>>>(x, text_mask, image_mask, gidx,
                                        Wm1, bm1, Wm2, bm2, Wm3, bm3, (float*)d_out);
}

// Round 3
// 1633.764 us; speedup vs baseline: 2.0776x; 2.0776x over previous
//
#include <hip/hip_runtime.h>
#include <hip/hip_bf16.h>
#include <math.h>

#define Bb 16
#define Nn 512
#define Dd 256
#define Hh 8
#define HD 32
#define Ll 3
#define INDIM 768
#define Ee 4096
#define FF 1024

__device__ __forceinline__ float gelu_exact(float x) {
    return 0.5f * x * (1.0f + erff(x * 0.70710678118654752f));
}

// ---------------- edge bucketing ----------------

__global__ __launch_bounds__(256) void zero_kernel(int* __restrict__ p, int n) {
    int gid = blockIdx.x * 256 + threadIdx.x;
    if (gid < n) p[gid] = 0;
}

__global__ __launch_bounds__(256) void count_kernel(const int* __restrict__ edge_index,
                                                    int* __restrict__ counts) {
    int gid = blockIdx.x * 256 + threadIdx.x; // B*E = 65536
    int b = gid >> 12;
    int e = gid & (Ee - 1);
    int src = edge_index[b * 2 * Ee + e];
    atomicAdd(&counts[b * Nn + src], 1);
}

__global__ __launch_bounds__(1024) void scan_kernel(const int* __restrict__ counts,
                                                    int* __restrict__ offsets,
                                                    int* __restrict__ cursor) {
    __shared__ int ssum[1024];
    int t = threadIdx.x;
    int local[8];
    int s = 0;
#pragma unroll
    for (int i = 0; i < 8; i++) { local[i] = counts[t * 8 + i]; s += local[i]; }
    ssum[t] = s;
    __syncthreads();
    for (int off = 1; off < 1024; off *= 2) {
        __syncthreads();
        int v = (t >= off) ? ssum[t - off] : 0;
        __syncthreads();
        ssum[t] += v;
    }
    __syncthreads();
    int base = (t > 0) ? ssum[t - 1] : 0;
#pragma unroll
    for (int i = 0; i < 8; i++) {
        offsets[t * 8 + i] = base;
        cursor[t * 8 + i] = base;
        base += local[i];
    }
    if (t == 1023) offsets[8192] = base;
}

__global__ __launch_bounds__(256) void scatter_kernel(const int* __restrict__ edge_index,
                                                      int* __restrict__ cursor,
                                                      int* __restrict__ elist) {
    int gid = blockIdx.x * 256 + threadIdx.x;
    int b = gid >> 12;
    int e = gid & (Ee - 1);
    int src = edge_index[b * 2 * Ee + e];
    int pos = atomicAdd(&cursor[b * Nn + src], 1);
    elist[pos] = gid;
}

// ---------------- fp32 GEMM: 128x128 tile, 8x8/thread ----------------
// C = A(MxK) @ W(KxN) + bias, opt GELU.  M%128==0, N%128==0, K%16==0.

__global__ __launch_bounds__(256) void gemm128(const float* __restrict__ A,
                                               const float* __restrict__ W,
                                               const float* __restrict__ bias,
                                               float* __restrict__ C,
                                               int M, int K, int N, int act) {
    __shared__ float sA[16][128];  // [k][m]
    __shared__ float sB[16][128];  // [k][n]
    int t = threadIdx.x;
    int tx = t & 15, ty = t >> 4;
    int row0 = blockIdx.y * 128, col0 = blockIdx.x * 128;
    float acc[8][8] = {};
    int ar = t >> 1, ak = (t & 1) * 8;   // A staging: row ar, k-off ak
    int bk = t >> 4, bc = (t & 15) * 8;  // B staging

    for (int k0 = 0; k0 < K; k0 += 16) {
        float4 a0 = *(const float4*)&A[(size_t)(row0 + ar) * K + k0 + ak];
        float4 a1 = *(const float4*)&A[(size_t)(row0 + ar) * K + k0 + ak + 4];
        float4 b0 = *(const float4*)&W[(size_t)(k0 + bk) * N + col0 + bc];
        float4 b1 = *(const float4*)&W[(size_t)(k0 + bk) * N + col0 + bc + 4];
        __syncthreads();  // previous iter's reads done before overwrite
        sA[ak + 0][ar] = a0.x; sA[ak + 1][ar] = a0.y;
        sA[ak + 2][ar] = a0.z; sA[ak + 3][ar] = a0.w;
        sA[ak + 4][ar] = a1.x; sA[ak + 5][ar] = a1.y;
        sA[ak + 6][ar] = a1.z; sA[ak + 7][ar] = a1.w;
        *(float4*)&sB[bk][bc] = b0;
        *(float4*)&sB[bk][bc + 4] = b1;
        __syncthreads();
#pragma unroll
        for (int kk = 0; kk < 16; kk++) {
            float4 av0 = *(const float4*)&sA[kk][ty * 4];
            float4 av1 = *(const float4*)&sA[kk][64 + ty * 4];
            float4 bv0 = *(const float4*)&sB[kk][tx * 4];
            float4 bv1 = *(const float4*)&sB[kk][64 + tx * 4];
            float a[8] = {av0.x, av0.y, av0.z, av0.w, av1.x, av1.y, av1.z, av1.w};
            float bb[8] = {bv0.x, bv0.y, bv0.z, bv0.w, bv1.x, bv1.y, bv1.z, bv1.w};
#pragma unroll
            for (int i = 0; i < 8; i++)
#pragma unroll
                for (int j = 0; j < 8; j++) acc[i][j] += a[i] * bb[j];
        }
    }
#pragma unroll
    for (int i = 0; i < 8; i++) {
        int r = row0 + ((i < 4) ? (ty * 4 + i) : (64 + ty * 4 + i - 4));
#pragma unroll
        for (int jh = 0; jh < 2; jh++) {
            int c0 = col0 + jh * 64 + tx * 4;
            float4 v;
            float* vv = (float*)&v;
#pragma unroll
            for (int j = 0; j < 4; j++) {
                float u = acc[i][jh * 4 + j] + bias[c0 - col0 + col0 + j];  // bias[c0+j-?]
                vv[j] = u;
            }
            // fix bias indexing cleanly:
#pragma unroll
            for (int j = 0; j < 4; j++) {
                float u = acc[i][jh * 4 + j] + bias[c0 + j];
                if (act == 1) u = gelu_exact(u);
                vv[j] = u;
            }
            *(float4*)&C[(size_t)r * N + c0] = v;
        }
    }
}

// ---------------- attention v2: one block per (b,h,half), 512 threads ----------------

__global__ __launch_bounds__(512, 1) void attn_kernel(const float* __restrict__ qkv,
                                                      const int* __restrict__ node_mask,
                                                      const int* __restrict__ offsets,
                                                      const int* __restrict__ elist,
                                                      const int* __restrict__ edge_index,
                                                      const int* __restrict__ edge_type,
                                                      const float* __restrict__ edge_weight,
                                                      const float* __restrict__ et_emb,
                                                      float* __restrict__ outbuf) {
    int bid = blockIdx.x;          // b*16 + h*2 + half
    int half = bid & 1;
    int h = (bid >> 1) & 7;
    int b = bid >> 4;
    int t = threadIdx.x;
    int w = t >> 6;   // wave 0..7
    int L = t & 63;   // lane

    __shared__ __align__(16) float KT[HD][Nn];        // 64 KB, K transposed
    __shared__ __align__(16) float srow[8][4][Nn];    // 64 KB, per-wave 4 score rows
    __shared__ float qtile[8][4][HD];                 // 4 KB
    __shared__ float maskb[Nn];                       // 2 KB
    __shared__ float etl[4];

    // ---- stage KT (coalesced global read; 32-way LDS write conflict, once) ----
    for (int i = t; i < Nn * HD; i += 512) {
        int m = i >> 5, d = i & 31;
        KT[d][m] = qkv[(size_t)(b * Nn + m) * 768 + 256 + h * HD + d];
    }
    if (t < Nn) maskb[t] = node_mask[b * Nn + t] ? 0.0f : -INFINITY;
    if (t < 4) etl[t] = et_emb[t * Hh + h];
    __syncthreads();

    const float scale = 0.17677669529663687f;  // 1/sqrt(32)
    int base = half * 256;

    for (int g = 0; g < 8; g++) {
        int n0 = base + w * 32 + g * 4;  // 4 consecutive rows n0..n0+3

        // ---- q into LDS (per wave) ----
        for (int i = L; i < 4 * HD; i += 64) {
            int r = i >> 5, d = i & 31;
            qtile[w][r][d] = qkv[(size_t)(b * Nn + n0 + r) * 768 + h * HD + d] * scale;
        }
        asm volatile("s_waitcnt lgkmcnt(0) vmcnt(0)" ::: "memory");

        // ---- QK^T: s[r][k], m = L + 64k ----
        float acc[4][8];
#pragma unroll
        for (int r = 0; r < 4; r++)
#pragma unroll
            for (int k = 0; k < 8; k++) acc[r][k] = 0.0f;
#pragma unroll 8
        for (int d = 0; d < HD; d++) {
            float q0 = qtile[w][0][d], q1 = qtile[w][1][d];
            float q2 = qtile[w][2][d], q3 = qtile[w][3][d];
#pragma unroll
            for (int k = 0; k < 8; k++) {
                float kv = KT[d][L + 64 * k];
                acc[0][k] += q0 * kv;
                acc[1][k] += q1 * kv;
                acc[2][k] += q2 * kv;
                acc[3][k] += q3 * kv;
            }
        }

        // ---- raw scores to LDS ----
#pragma unroll
        for (int r = 0; r < 4; r++)
#pragma unroll
            for (int k = 0; k < 8; k++) srow[w][r][L + 64 * k] = acc[r][k];
        asm volatile("s_waitcnt lgkmcnt(0)" ::: "memory");

        // ---- edge bias replay (buckets for rows n0..n0+3 are contiguous) ----
        int beg = offsets[b * Nn + n0];
        int end = offsets[b * Nn + n0 + 4];
        for (int i = beg + L; i < end; i += 64) {
            int ge = elist[i];
            int e = ge & (Ee - 1);
            int src = edge_index[b * 2 * Ee + e];
            int dst = edge_index[b * 2 * Ee + Ee + e];
            int ty = edge_type[b * Ee + e];
            float wgt = edge_weight[b * Ee + e];
            float val = etl[ty] + (ty == 2 ? wgt : 0.0f);
            atomicAdd(&srow[w][src - n0][dst], val);
        }
        asm volatile("s_waitcnt lgkmcnt(0)" ::: "memory");

        // ---- read back + mask + softmax (per-wave, registers + shuffles) ----
        float mb[8];
#pragma unroll
        for (int k = 0; k < 8; k++) mb[k] = maskb[L + 64 * k];
        float inv[4];
#pragma unroll
        for (int r = 0; r < 4; r++) {
            float s[8];
#pragma unroll
            for (int k = 0; k < 8; k++) s[k] = srow[w][r][L + 64 * k] + mb[k];
            float mx = s[0];
#pragma unroll
            for (int k = 1; k < 8; k++) mx = fmaxf(mx, s[k]);
#pragma unroll
            for (int o = 1; o < 64; o <<= 1) mx = fmaxf(mx, __shfl_xor(mx, o));
            float sum = 0.0f;
#pragma unroll
            for (int k = 0; k < 8; k++) {
                s[k] = __expf(s[k] - mx);
                sum += s[k];
            }
#pragma unroll
            for (int o = 1; o < 64; o <<= 1) sum += __shfl_xor(sum, o);
            inv[r] = 1.0f / sum;
#pragma unroll
            for (int k = 0; k < 8; k++) srow[w][r][L + 64 * k] = s[k];
        }
        asm volatile("s_waitcnt lgkmcnt(0)" ::: "memory");

        // ---- PV: lane = (d, half-of-m); V streamed from global (coalesced) ----
        int d = L & 31, h2 = L >> 5;
        int mbase = h2 * 256;
        const float* vp = qkv + (size_t)(b * Nn + mbase) * 768 + 512 + h * HD + d;
        float o0 = 0.0f, o1 = 0.0f, o2 = 0.0f, o3 = 0.0f;
#pragma unroll 4
        for (int mc = 0; mc < 256; mc += 4) {
            float v0 = vp[(size_t)(mc + 0) * 768];
            float v1 = vp[(size_t)(mc + 1) * 768];
            float v2 = vp[(size_t)(mc + 2) * 768];
            float v3 = vp[(size_t)(mc + 3) * 768];
            float4 s0 = *(const float4*)&srow[w][0][mbase + mc];
            float4 s1 = *(const float4*)&srow[w][1][mbase + mc];
            float4 s2 = *(const float4*)&srow[w][2][mbase + mc];
            float4 s3 = *(const float4*)&srow[w][3][mbase + mc];
            o0 += s0.x * v0 + s0.y * v1 + s0.z * v2 + s0.w * v3;
            o1 += s1.x * v0 + s1.y * v1 + s1.z * v2 + s1.w * v3;
            o2 += s2.x * v0 + s2.y * v1 + s2.z * v2 + s2.w * v3;
            o3 += s3.x * v0 + s3.y * v1 + s3.z * v2 + s3.w * v3;
        }
        // combine m-halves
        o0 += __shfl_xor(o0, 32);
        o1 += __shfl_xor(o1, 32);
        o2 += __shfl_xor(o2, 32);
        o3 += __shfl_xor(o3, 32);
        if (h2 == 0) {
            outbuf[(size_t)(b * Nn + n0 + 0) * Dd + h * HD + d] = o0 * inv[0];
            outbuf[(size_t)(b * Nn + n0 + 1) * Dd + h * HD + d] = o1 * inv[1];
            outbuf[(size_t)(b * Nn + n0 + 2) * Dd + h * HD + d] = o2 * inv[2];
            outbuf[(size_t)(b * Nn + n0 + 3) * Dd + h * HD + d] = o3 * inv[3];
        }
    }
}

// ---------------- residual + LayerNorm ----------------

__global__ __launch_bounds__(256) void ln_kernel(float* __restrict__ x,
                                                 const float* __restrict__ res,
                                                 const float* __restrict__ g,
                                                 const float* __restrict__ bta) {
    int row = blockIdx.x;
    int t = threadIdx.x;
    __shared__ float red[4];
    __shared__ float stats[2];
    size_t idx = (size_t)row * Dd + t;
    float v = x[idx] + res[idx];
    float sm = v;
    for (int o = 32; o > 0; o >>= 1) sm += __shfl_down(sm, o);
    if ((t & 63) == 0) red[t >> 6] = sm;
    __syncthreads();
    if (t == 0) stats[0] = (red[0] + red[1] + red[2] + red[3]) * (1.0f / Dd);
    __syncthreads();
    float mu = stats[0];
    float dv = v - mu;
    float s2 = dv * dv;
    for (int o = 32; o > 0; o >>= 1) s2 += __shfl_down(s2, o);
    if ((t & 63) == 0) red[t >> 6] = s2;
    __syncthreads();
    if (t == 0) stats[1] = 1.0f / sqrtf((red[0] + red[1] + red[2] + red[3]) * (1.0f / Dd) + 1e-5f);
    __syncthreads();
    x[idx] = dv * stats[1] * g[t] + bta[t];
}

// ---------------- head ----------------

__global__ __launch_bounds__(256) void head_kernel(const float* __restrict__ x,
                                                   const int* __restrict__ text_mask,
                                                   const int* __restrict__ image_mask,
                                                   const int* __restrict__ gidx,
                                                   const float* __restrict__ Wm1,
                                                   const float* __restrict__ bm1,
                                                   const float* __restrict__ Wm2,
                                                   const float* __restrict__ bm2,
                                                   const float* __restrict__ Wm3,
                                                   const float* __restrict__ bm3,
                                                   float* __restrict__ out) {
    int b = blockIdx.x;
    int t = threadIdx.x;
    __shared__ float comb[769];
    __shared__ float h1[512];
    __shared__ float h2[256];
    __shared__ float redc[8];
    __shared__ float redd[12];
    __shared__ float red[4];

    float tp = 0.0f, ip = 0.0f;
    for (int n = 0; n < Nn; n++) {
        float xv = x[(size_t)(b * Nn + n) * Dd + t];
        tp += xv * (float)text_mask[b * Nn + n];
        ip += xv * (float)image_mask[b * Nn + n];
    }
    float c1 = 0.0f, c2 = 0.0f;
    for (int n = t; n < Nn; n += 256) {
        c1 += (float)text_mask[b * Nn + n];
        c2 += (float)image_mask[b * Nn + n];
    }
    for (int o = 32; o > 0; o >>= 1) { c1 += __shfl_down(c1, o); c2 += __shfl_down(c2, o); }
    if ((t & 63) == 0) { redc[t >> 6] = c1; redc[4 + (t >> 6)] = c2; }
    __syncthreads();
    float tc = fmaxf(redc[0] + redc[1] + redc[2] + redc[3], 1.0f);
    float ic = fmaxf(redc[4] + redc[5] + redc[6] + redc[7], 1.0f);
    tp /= tc;
    ip /= ic;

    int gi = gidx[b];
    comb[t] = x[(size_t)(b * Nn + gi) * Dd + t];
    comb[256 + t] = tp;
    comb[512 + t] = ip;

    float dotv = tp * ip, n1v = tp * tp, n2v = ip * ip;
    for (int o = 32; o > 0; o >>= 1) {
        dotv += __shfl_down(dotv, o);
        n1v += __shfl_down(n1v, o);
        n2v += __shfl_down(n2v, o);
    }
    if ((t & 63) == 0) { redd[t >> 6] = dotv; redd[4 + (t >> 6)] = n1v; redd[8 + (t >> 6)] = n2v; }
    __syncthreads();
    if (t == 0) {
        float dd = redd[0] + redd[1] + redd[2] + redd[3];
        float a1 = fmaxf(sqrtf(redd[4] + redd[5] + redd[6] + redd[7]), 1e-6f);
        float a2 = fmaxf(sqrtf(redd[8] + redd[9] + redd[10] + redd[11]), 1e-6f);
        comb[768] = 1.0f - dd / (a1 * a2);
    }
    __syncthreads();

#pragma unroll
    for (int jj = 0; jj < 2; jj++) {
        int j = t + jj * 256;
        float acc = bm1[j];
        for (int k = 0; k < 769; k++) acc += comb[k] * Wm1[k * 512 + j];
        h1[j] = gelu_exact(acc);
    }
    __syncthreads();
    {
        float acc = bm2[t];
        for (int k = 0; k < 512; k++) acc += h1[k] * Wm2[k * 256 + t];
        h2[t] = gelu_exact(acc);
    }
    __syncthreads();
    float lv = h2[t] * Wm3[t];
    for (int o = 32; o > 0; o >>= 1) lv += __shfl_down(lv, o);
    if ((t & 63) == 0) red[t >> 6] = lv;
    __syncthreads();
    if (t == 0) out[b] = red[0] + red[1] + red[2] + red[3] + bm3[0];
}

// ---------------- launch ----------------

extern "C" void kernel_launch(void* const* d_in, const int* in_sizes, int n_in,
                              void* d_out, int out_size, void* d_ws, size_t ws_size,
                              hipStream_t stream) {
    const float* node_feats = (const float*)d_in[0];
    const int* node_mask = (const int*)d_in[1];
    const int* text_mask = (const int*)d_in[2];
    const int* image_mask = (const int*)d_in[3];
    const int* gidx = (const int*)d_in[4];
    const int* edge_index = (const int*)d_in[5];
    const int* edge_type = (const int*)d_in[6];
    const float* edge_weight = (const float*)d_in[7];
    const float* W_in = (const float*)d_in[8];
    const float* b_in = (const float*)d_in[9];
    const float* Wqkv = (const float*)d_in[10];
    const float* bqkv = (const float*)d_in[11];
    const float* Wo = (const float*)d_in[12];
    const float* bo = (const float*)d_in[13];
    const float* ln1_g = (const float*)d_in[14];
    const float* ln1_b = (const float*)d_in[15];
    const float* ln2_g = (const float*)d_in[16];
    const float* ln2_b = (const float*)d_in[17];
    const float* Wff1 = (const float*)d_in[18];
    const float* bff1 = (const float*)d_in[19];
    const float* Wff2 = (const float*)d_in[20];
    const float* bff2 = (const float*)d_in[21];
    const float* et_emb = (const float*)d_in[22];
    const float* Wm1 = (const float*)d_in[23];
    const float* bm1 = (const float*)d_in[24];
    const float* Wm2 = (const float*)d_in[25];
    const float* bm2 = (const float*)d_in[26];
    const float* Wm3 = (const float*)d_in[27];
    const float* bm3 = (const float*)d_in[28];

    const int M = Bb * Nn; // 8192
    char* ws = (char*)d_ws;
    size_t off = 0;
    auto alloc = [&](size_t bytes) {
        void* p = ws + off;
        off += (bytes + 255) & ~(size_t)255;
        return p;
    };
    float* x = (float*)alloc((size_t)M * Dd * 4);        // 8 MB
    float* qkvb = (float*)alloc((size_t)M * FF * 4);     // 32 MB union (qkv 24MB / ff 32MB)
    float* ffb = qkvb;
    float* attnout = (float*)alloc((size_t)M * Dd * 4);  // 8 MB
    float* projb = (float*)alloc((size_t)M * Dd * 4);    // 8 MB
    int* counts = (int*)alloc(8192 * 4);
    int* offsets = (int*)alloc(8193 * 4);
    int* cursor = (int*)alloc(8192 * 4);
    int* elist = (int*)alloc((size_t)Bb * Ee * 4);
    (void)ws_size;

    zero_kernel<<<32, 256, 0, stream>>>(counts, 8192);
    count_kernel<<<256, 256, 0, stream>>>(edge_index, counts);
    scan_kernel<<<1, 1024, 0, stream>>>(counts, offsets, cursor);
    scatter_kernel<<<256, 256, 0, stream>>>(edge_index, cursor, elist);

    gemm128<<<dim3(Dd / 128, M / 128), 256, 0, stream>>>(node_feats, W_in, b_in, x, M, INDIM, Dd, 0);

    for (int l = 0; l < Ll; l++) {
        gemm128<<<dim3(768 / 128, M / 128), 256, 0, stream>>>(
            x, Wqkv + (size_t)l * Dd * 768, bqkv + l * 768, qkvb, M, Dd, 768, 0);
        attn_kernel<<<Bb * Hh * 2, 512, 0, stream>>>(
            qkvb, node_mask, offsets, elist, edge_index, edge_type, edge_weight, et_emb, attnout);
        gemm128<<<dim3(Dd / 128, M / 128), 256, 0, stream>>>(
            attnout, Wo + (size_t)l * Dd * Dd, bo + l * Dd, projb, M, Dd, Dd, 0);
        ln_kernel<<<M, 256, 0, stream>>>(x, projb, ln1_g + l * Dd, ln1_b + l * Dd);
        gemm128<<<dim3(FF / 128, M / 128), 256, 0, stream>>>(
            x, Wff1 + (size_t)l * Dd * FF, bff1 + l * FF, ffb, M, Dd, FF, 1);
        gemm128<<<dim3(Dd / 128, M / 128), 256, 0, stream>>>(
            ffb, Wff2 + (size_t)l * FF * Dd, bff2 + l * Dd, projb, M, FF, Dd, 0);
        ln_kernel<<<M, 256, 0, stream>>>(x, projb, ln2_g + l * Dd, ln2_b + l * Dd);
    }

    head_kernel<<<Bb, 256, 0, stream>>>(x, text_mask, image_mask, gidx,
                                        Wm1, bm1, Wm2, bm2, Wm3, bm3, (float*)d_out);
}

// Round 4
// 1600.334 us; speedup vs baseline: 2.1210x; 1.0209x over previous
//
#include <hip/hip_runtime.h>
#include <hip/hip_bf16.h>
#include <math.h>

#define Bb 16
#define Nn 512
#define Dd 256
#define Hh 8
#define HD 32
#define Ll 3
#define INDIM 768
#define Ee 4096
#define FF 1024
#define KTP 516  // KT row pitch (pad 4): b128-aligned, 4-way staging conflict (free-ish)

__device__ __forceinline__ float gelu_exact(float x) {
    return 0.5f * x * (1.0f + erff(x * 0.70710678118654752f));
}

// ---------------- edge bucketing ----------------

__global__ __launch_bounds__(256) void zero_kernel(int* __restrict__ p, int n) {
    int gid = blockIdx.x * 256 + threadIdx.x;
    if (gid < n) p[gid] = 0;
}

__global__ __launch_bounds__(256) void count_kernel(const int* __restrict__ edge_index,
                                                    int* __restrict__ counts) {
    int gid = blockIdx.x * 256 + threadIdx.x; // B*E = 65536
    int b = gid >> 12;
    int e = gid & (Ee - 1);
    int src = edge_index[b * 2 * Ee + e];
    atomicAdd(&counts[b * Nn + src], 1);
}

__global__ __launch_bounds__(1024) void scan_kernel(const int* __restrict__ counts,
                                                    int* __restrict__ offsets,
                                                    int* __restrict__ cursor) {
    __shared__ int ssum[1024];
    int t = threadIdx.x;
    int local[8];
    int s = 0;
#pragma unroll
    for (int i = 0; i < 8; i++) { local[i] = counts[t * 8 + i]; s += local[i]; }
    ssum[t] = s;
    __syncthreads();
    for (int off = 1; off < 1024; off *= 2) {
        __syncthreads();
        int v = (t >= off) ? ssum[t - off] : 0;
        __syncthreads();
        ssum[t] += v;
    }
    __syncthreads();
    int base = (t > 0) ? ssum[t - 1] : 0;
#pragma unroll
    for (int i = 0; i < 8; i++) {
        offsets[t * 8 + i] = base;
        cursor[t * 8 + i] = base;
        base += local[i];
    }
    if (t == 1023) offsets[8192] = base;
}

__global__ __launch_bounds__(256) void scatter_kernel(const int* __restrict__ edge_index,
                                                      int* __restrict__ cursor,
                                                      int* __restrict__ elist) {
    int gid = blockIdx.x * 256 + threadIdx.x;
    int b = gid >> 12;
    int e = gid & (Ee - 1);
    int src = edge_index[b * 2 * Ee + e];
    int pos = atomicAdd(&cursor[b * Nn + src], 1);
    elist[pos] = gid;
}

// ---------------- fp32 GEMM: 128x128 tile, 8x8/thread ----------------

__global__ __launch_bounds__(256) void gemm128(const float* __restrict__ A,
                                               const float* __restrict__ W,
                                               const float* __restrict__ bias,
                                               float* __restrict__ C,
                                               int M, int K, int N, int act) {
    __shared__ float sA[16][128];  // [k][m]
    __shared__ float sB[16][128];  // [k][n]
    int t = threadIdx.x;
    int tx = t & 15, ty = t >> 4;
    int row0 = blockIdx.y * 128, col0 = blockIdx.x * 128;
    float acc[8][8] = {};
    int ar = t >> 1, ak = (t & 1) * 8;
    int bk = t >> 4, bc = (t & 15) * 8;

    for (int k0 = 0; k0 < K; k0 += 16) {
        float4 a0 = *(const float4*)&A[(size_t)(row0 + ar) * K + k0 + ak];
        float4 a1 = *(const float4*)&A[(size_t)(row0 + ar) * K + k0 + ak + 4];
        float4 b0 = *(const float4*)&W[(size_t)(k0 + bk) * N + col0 + bc];
        float4 b1 = *(const float4*)&W[(size_t)(k0 + bk) * N + col0 + bc + 4];
        __syncthreads();
        sA[ak + 0][ar] = a0.x; sA[ak + 1][ar] = a0.y;
        sA[ak + 2][ar] = a0.z; sA[ak + 3][ar] = a0.w;
        sA[ak + 4][ar] = a1.x; sA[ak + 5][ar] = a1.y;
        sA[ak + 6][ar] = a1.z; sA[ak + 7][ar] = a1.w;
        *(float4*)&sB[bk][bc] = b0;
        *(float4*)&sB[bk][bc + 4] = b1;
        __syncthreads();
#pragma unroll
        for (int kk = 0; kk < 16; kk++) {
            float4 av0 = *(const float4*)&sA[kk][ty * 4];
            float4 av1 = *(const float4*)&sA[kk][64 + ty * 4];
            float4 bv0 = *(const float4*)&sB[kk][tx * 4];
            float4 bv1 = *(const float4*)&sB[kk][64 + tx * 4];
            float a[8] = {av0.x, av0.y, av0.z, av0.w, av1.x, av1.y, av1.z, av1.w};
            float bb[8] = {bv0.x, bv0.y, bv0.z, bv0.w, bv1.x, bv1.y, bv1.z, bv1.w};
#pragma unroll
            for (int i = 0; i < 8; i++)
#pragma unroll
                for (int j = 0; j < 8; j++) acc[i][j] += a[i] * bb[j];
        }
    }
#pragma unroll
    for (int i = 0; i < 8; i++) {
        int r = row0 + ((i < 4) ? (ty * 4 + i) : (64 + ty * 4 + i - 4));
#pragma unroll
        for (int jh = 0; jh < 2; jh++) {
            int c0 = col0 + jh * 64 + tx * 4;
            float4 v;
            float* vv = (float*)&v;
#pragma unroll
            for (int j = 0; j < 4; j++) {
                float u = acc[i][jh * 4 + j] + bias[c0 + j];
                if (act == 1) u = gelu_exact(u);
                vv[j] = u;
            }
            *(float4*)&C[(size_t)r * N + c0] = v;
        }
    }
}

// ---------------- attention v3: one block per (b,h,half), 512 threads ----------------
// Lane ownership in QK/softmax: m = 8*L + j (j=0..7) -> all KT/srow traffic is b128.

__global__ __launch_bounds__(512, 1) void attn_kernel(const float* __restrict__ qkv,
                                                      const int* __restrict__ node_mask,
                                                      const int* __restrict__ offsets,
                                                      const int* __restrict__ elist,
                                                      const int* __restrict__ edge_index,
                                                      const int* __restrict__ edge_type,
                                                      const float* __restrict__ edge_weight,
                                                      const float* __restrict__ et_emb,
                                                      float* __restrict__ outbuf) {
    int bid = blockIdx.x;          // b*16 + h*2 + half
    int half = bid & 1;
    int h = (bid >> 1) & 7;
    int b = bid >> 4;
    int t = threadIdx.x;
    int w = t >> 6;   // wave 0..7
    int L = t & 63;   // lane

    __shared__ __align__(16) float KT[HD][KTP];       // ~64.5 KB, K transposed, padded
    __shared__ __align__(16) float srow[8][4][Nn];    // 64 KB, per-wave 4 score rows
    __shared__ __align__(16) float maskb[Nn];         // 2 KB
    __shared__ float qtile[8][4][HD];                 // 4 KB
    __shared__ float etl[4];

    // ---- stage KT: coalesced global (lanes sweep d), 4-way LDS write conflict ----
    for (int i = t; i < Nn * HD; i += 512) {
        int m = i >> 5, d = i & 31;
        KT[d][m] = qkv[(size_t)(b * Nn + m) * 768 + 256 + h * HD + d];
    }
    if (t < Nn) maskb[t] = node_mask[b * Nn + t] ? 0.0f : -INFINITY;
    if (t < 4) etl[t] = et_emb[t * Hh + h];
    __syncthreads();

    const float scale = 0.17677669529663687f;  // 1/sqrt(32)
    int base = half * 256;
    int m8 = 8 * L;

    // mask for owned m (loop-invariant)
    float4 mb0 = *(const float4*)&maskb[m8];
    float4 mb1 = *(const float4*)&maskb[m8 + 4];
    float mb[8] = {mb0.x, mb0.y, mb0.z, mb0.w, mb1.x, mb1.y, mb1.z, mb1.w};

    for (int g = 0; g < 8; g++) {
        int n0 = base + w * 32 + g * 4;  // 4 consecutive rows

        // ---- q into LDS (per wave) ----
        for (int i = L; i < 4 * HD; i += 64) {
            int r = i >> 5, d = i & 31;
            qtile[w][r][d] = qkv[(size_t)(b * Nn + n0 + r) * 768 + h * HD + d] * scale;
        }
        asm volatile("s_waitcnt lgkmcnt(0) vmcnt(0)" ::: "memory");

        // ---- QK^T: acc[r][j], m = 8L+j; KT read as 2x b128 (contiguous row sweep) ----
        float acc[4][8];
#pragma unroll
        for (int r = 0; r < 4; r++)
#pragma unroll
            for (int j = 0; j < 8; j++) acc[r][j] = 0.0f;
#pragma unroll 4
        for (int d = 0; d < HD; d++) {
            float4 k0 = *(const float4*)&KT[d][m8];
            float4 k1 = *(const float4*)&KT[d][m8 + 4];
            float kk[8] = {k0.x, k0.y, k0.z, k0.w, k1.x, k1.y, k1.z, k1.w};
            float q0 = qtile[w][0][d], q1 = qtile[w][1][d];
            float q2 = qtile[w][2][d], q3 = qtile[w][3][d];
#pragma unroll
            for (int j = 0; j < 8; j++) {
                acc[0][j] += q0 * kk[j];
                acc[1][j] += q1 * kk[j];
                acc[2][j] += q2 * kk[j];
                acc[3][j] += q3 * kk[j];
            }
        }

        // ---- raw scores to LDS (b128, contiguous) ----
#pragma unroll
        for (int r = 0; r < 4; r++) {
            *(float4*)&srow[w][r][m8] = make_float4(acc[r][0], acc[r][1], acc[r][2], acc[r][3]);
            *(float4*)&srow[w][r][m8 + 4] = make_float4(acc[r][4], acc[r][5], acc[r][6], acc[r][7]);
        }
        asm volatile("s_waitcnt lgkmcnt(0)" ::: "memory");

        // ---- edge bias replay (buckets for rows n0..n0+3 contiguous in elist) ----
        int beg = offsets[b * Nn + n0];
        int end = offsets[b * Nn + n0 + 4];
        for (int i = beg + L; i < end; i += 64) {
            int ge = elist[i];
            int e = ge & (Ee - 1);
            int src = edge_index[b * 2 * Ee + e];
            int dst = edge_index[b * 2 * Ee + Ee + e];
            int ty = edge_type[b * Ee + e];
            float wgt = edge_weight[b * Ee + e];
            float val = etl[ty] + (ty == 2 ? wgt : 0.0f);
            atomicAdd(&srow[w][src - n0][dst], val);
        }
        asm volatile("s_waitcnt lgkmcnt(0)" ::: "memory");

        // ---- read back (b128) + mask + softmax in registers ----
        float inv[4];
#pragma unroll
        for (int r = 0; r < 4; r++) {
            float4 s0 = *(const float4*)&srow[w][r][m8];
            float4 s1 = *(const float4*)&srow[w][r][m8 + 4];
            float s[8] = {s0.x, s0.y, s0.z, s0.w, s1.x, s1.y, s1.z, s1.w};
#pragma unroll
            for (int j = 0; j < 8; j++) s[j] += mb[j];
            float mx = s[0];
#pragma unroll
            for (int j = 1; j < 8; j++) mx = fmaxf(mx, s[j]);
#pragma unroll
            for (int o = 1; o < 64; o <<= 1) mx = fmaxf(mx, __shfl_xor(mx, o));
            float sum = 0.0f;
#pragma unroll
            for (int j = 0; j < 8; j++) {
                s[j] = __expf(s[j] - mx);
                sum += s[j];
            }
#pragma unroll
            for (int o = 1; o < 64; o <<= 1) sum += __shfl_xor(sum, o);
            inv[r] = 1.0f / sum;
            *(float4*)&srow[w][r][m8] = make_float4(s[0], s[1], s[2], s[3]);
            *(float4*)&srow[w][r][m8 + 4] = make_float4(s[4], s[5], s[6], s[7]);
        }
        asm volatile("s_waitcnt lgkmcnt(0)" ::: "memory");

        // ---- PV: lane = (d, m-half); V streamed from global (coalesced) ----
        int d = L & 31, h2 = L >> 5;
        int mbase = h2 * 256;
        const float* vp = qkv + (size_t)(b * Nn + mbase) * 768 + 512 + h * HD + d;
        float o0 = 0.0f, o1 = 0.0f, o2 = 0.0f, o3 = 0.0f;
#pragma unroll 4
        for (int mc = 0; mc < 256; mc += 4) {
            float v0 = vp[(size_t)(mc + 0) * 768];
            float v1 = vp[(size_t)(mc + 1) * 768];
            float v2 = vp[(size_t)(mc + 2) * 768];
            float v3 = vp[(size_t)(mc + 3) * 768];
            float4 s0 = *(const float4*)&srow[w][0][mbase + mc];
            float4 s1 = *(const float4*)&srow[w][1][mbase + mc];
            float4 s2 = *(const float4*)&srow[w][2][mbase + mc];
            float4 s3 = *(const float4*)&srow[w][3][mbase + mc];
            o0 += s0.x * v0 + s0.y * v1 + s0.z * v2 + s0.w * v3;
            o1 += s1.x * v0 + s1.y * v1 + s1.z * v2 + s1.w * v3;
            o2 += s2.x * v0 + s2.y * v1 + s2.z * v2 + s2.w * v3;
            o3 += s3.x * v0 + s3.y * v1 + s3.z * v2 + s3.w * v3;
        }
        o0 += __shfl_xor(o0, 32);
        o1 += __shfl_xor(o1, 32);
        o2 += __shfl_xor(o2, 32);
        o3 += __shfl_xor(o3, 32);
        if (h2 == 0) {
            outbuf[(size_t)(b * Nn + n0 + 0) * Dd + h * HD + d] = o0 * inv[0];
            outbuf[(size_t)(b * Nn + n0 + 1) * Dd + h * HD + d] = o1 * inv[1];
            outbuf[(size_t)(b * Nn + n0 + 2) * Dd + h * HD + d] = o2 * inv[2];
            outbuf[(size_t)(b * Nn + n0 + 3) * Dd + h * HD + d] = o3 * inv[3];
        }
    }
}

// ---------------- residual + LayerNorm ----------------

__global__ __launch_bounds__(256) void ln_kernel(float* __restrict__ x,
                                                 const float* __restrict__ res,
                                                 const float* __restrict__ g,
                                                 const float* __restrict__ bta) {
    int row = blockIdx.x;
    int t = threadIdx.x;
    __shared__ float red[4];
    __shared__ float stats[2];
    size_t idx = (size_t)row * Dd + t;
    float v = x[idx] + res[idx];
    float sm = v;
    for (int o = 32; o > 0; o >>= 1) sm += __shfl_down(sm, o);
    if ((t & 63) == 0) red[t >> 6] = sm;
    __syncthreads();
    if (t == 0) stats[0] = (red[0] + red[1] + red[2] + red[3]) * (1.0f / Dd);
    __syncthreads();
    float mu = stats[0];
    float dv = v - mu;
    float s2 = dv * dv;
    for (int o = 32; o > 0; o >>= 1) s2 += __shfl_down(s2, o);
    if ((t & 63) == 0) red[t >> 6] = s2;
    __syncthreads();
    if (t == 0) stats[1] = 1.0f / sqrtf((red[0] + red[1] + red[2] + red[3]) * (1.0f / Dd) + 1e-5f);
    __syncthreads();
    x[idx] = dv * stats[1] * g[t] + bta[t];
}

// ---------------- head: parallel pooling + small MLP ----------------
// pools layout per b (stride 514): [0..255]=text sum, [256..511]=image sum, [512]=tc, [513]=ic

__global__ __launch_bounds__(256) void pool_kernel(const float* __restrict__ x,
                                                   const int* __restrict__ text_mask,
                                                   const int* __restrict__ image_mask,
                                                   float* __restrict__ pools) {
    int b = blockIdx.y;
    int n0 = blockIdx.x * 32;  // 16 chunks of 32 rows
    int t = threadIdx.x;
    float tp = 0.0f, ip = 0.0f, c1 = 0.0f, c2 = 0.0f;
    for (int n = n0; n < n0 + 32; n++) {
        float xv = x[(size_t)(b * Nn + n) * Dd + t];
        int tm = text_mask[b * Nn + n];
        int im = image_mask[b * Nn + n];
        tp += tm ? xv : 0.0f;
        ip += im ? xv : 0.0f;
        c1 += (float)tm;
        c2 += (float)im;
    }
    atomicAdd(&pools[b * 514 + t], tp);
    atomicAdd(&pools[b * 514 + 256 + t], ip);
    if (t == 0) {
        atomicAdd(&pools[b * 514 + 512], c1);
        atomicAdd(&pools[b * 514 + 513], c2);
    }
}

__global__ __launch_bounds__(256) void head_mlp(const float* __restrict__ x,
                                                const float* __restrict__ pools,
                                                const int* __restrict__ gidx,
                                                const float* __restrict__ Wm1,
                                                const float* __restrict__ bm1,
                                                const float* __restrict__ Wm2,
                                                const float* __restrict__ bm2,
                                                const float* __restrict__ Wm3,
                                                const float* __restrict__ bm3,
                                                float* __restrict__ out) {
    int b = blockIdx.x;
    int t = threadIdx.x;
    __shared__ float comb[769];
    __shared__ float h1[512];
    __shared__ float h2[256];
    __shared__ float redd[12];
    __shared__ float red[4];

    float tc = fmaxf(pools[b * 514 + 512], 1.0f);
    float ic = fmaxf(pools[b * 514 + 513], 1.0f);
    float tp = pools[b * 514 + t] / tc;
    float ip = pools[b * 514 + 256 + t] / ic;

    int gi = gidx[b];
    comb[t] = x[(size_t)(b * Nn + gi) * Dd + t];
    comb[256 + t] = tp;
    comb[512 + t] = ip;

    float dotv = tp * ip, n1v = tp * tp, n2v = ip * ip;
    for (int o = 32; o > 0; o >>= 1) {
        dotv += __shfl_down(dotv, o);
        n1v += __shfl_down(n1v, o);
        n2v += __shfl_down(n2v, o);
    }
    if ((t & 63) == 0) { redd[t >> 6] = dotv; redd[4 + (t >> 6)] = n1v; redd[8 + (t >> 6)] = n2v; }
    __syncthreads();
    if (t == 0) {
        float dd = redd[0] + redd[1] + redd[2] + redd[3];
        float a1 = fmaxf(sqrtf(redd[4] + redd[5] + redd[6] + redd[7]), 1e-6f);
        float a2 = fmaxf(sqrtf(redd[8] + redd[9] + redd[10] + redd[11]), 1e-6f);
        comb[768] = 1.0f - dd / (a1 * a2);
    }
    __syncthreads();

#pragma unroll
    for (int jj = 0; jj < 2; jj++) {
        int j = t + jj * 256;
        float acc = bm1[j];
        for (int k = 0; k < 769; k++) acc += comb[k] * Wm1[k * 512 + j];
        h1[j] = gelu_exact(acc);
    }
    __syncthreads();
    {
        float acc = bm2[t];
        for (int k = 0; k < 512; k++) acc += h1[k] * Wm2[k * 256 + t];
        h2[t] = gelu_exact(acc);
    }
    __syncthreads();
    float lv = h2[t] * Wm3[t];
    for (int o = 32; o > 0; o >>= 1) lv += __shfl_down(lv, o);
    if ((t & 63) == 0) red[t >> 6] = lv;
    __syncthreads();
    if (t == 0) out[b] = red[0] + red[1] + red[2] + red[3] + bm3[0];
}

// ---------------- launch ----------------

extern "C" void kernel_launch(void* const* d_in, const int* in_sizes, int n_in,
                              void* d_out, int out_size, void* d_ws, size_t ws_size,
                              hipStream_t stream) {
    const float* node_feats = (const float*)d_in[0];
    const int* node_mask = (const int*)d_in[1];
    const int* text_mask = (const int*)d_in[2];
    const int* image_mask = (const int*)d_in[3];
    const int* gidx = (const int*)d_in[4];
    const int* edge_index = (const int*)d_in[5];
    const int* edge_type = (const int*)d_in[6];
    const float* edge_weight = (const float*)d_in[7];
    const float* W_in = (const float*)d_in[8];
    const float* b_in = (const float*)d_in[9];
    const float* Wqkv = (const float*)d_in[10];
    const float* bqkv = (const float*)d_in[11];
    const float* Wo = (const float*)d_in[12];
    const float* bo = (const float*)d_in[13];
    const float* ln1_g = (const float*)d_in[14];
    const float* ln1_b = (const float*)d_in[15];
    const float* ln2_g = (const float*)d_in[16];
    const float* ln2_b = (const float*)d_in[17];
    const float* Wff1 = (const float*)d_in[18];
    const float* bff1 = (const float*)d_in[19];
    const float* Wff2 = (const float*)d_in[20];
    const float* bff2 = (const float*)d_in[21];
    const float* et_emb = (const float*)d_in[22];
    const float* Wm1 = (const float*)d_in[23];
    const float* bm1 = (const float*)d_in[24];
    const float* Wm2 = (const float*)d_in[25];
    const float* bm2 = (const float*)d_in[26];
    const float* Wm3 = (const float*)d_in[27];
    const float* bm3 = (const float*)d_in[28];

    const int M = Bb * Nn; // 8192
    char* ws = (char*)d_ws;
    size_t off = 0;
    auto alloc = [&](size_t bytes) {
        void* p = ws + off;
        off += (bytes + 255) & ~(size_t)255;
        return p;
    };
    float* x = (float*)alloc((size_t)M * Dd * 4);        // 8 MB
    float* qkvb = (float*)alloc((size_t)M * FF * 4);     // 32 MB union (qkv 24MB / ff 32MB)
    float* ffb = qkvb;
    float* attnout = (float*)alloc((size_t)M * Dd * 4);  // 8 MB
    float* projb = (float*)alloc((size_t)M * Dd * 4);    // 8 MB
    int* counts = (int*)alloc(8192 * 4);
    int* offsets = (int*)alloc(8193 * 4);
    int* cursor = (int*)alloc(8192 * 4);
    int* elist = (int*)alloc((size_t)Bb * Ee * 4);
    float* pools = (float*)alloc((size_t)Bb * 514 * 4);
    (void)ws_size;

    zero_kernel<<<32, 256, 0, stream>>>(counts, 8192);
    zero_kernel<<<(Bb * 514 + 255) / 256, 256, 0, stream>>>((int*)pools, Bb * 514);
    count_kernel<<<256, 256, 0, stream>>>(edge_index, counts);
    scan_kernel<<<1, 1024, 0, stream>>>(counts, offsets, cursor);
    scatter_kernel<<<256, 256, 0, stream>>>(edge_index, cursor, elist);

    gemm128<<<dim3(Dd / 128, M / 128), 256, 0, stream>>>(node_feats, W_in, b_in, x, M, INDIM, Dd, 0);

    for (int l = 0; l < Ll; l++) {
        gemm128<<<dim3(768 / 128, M / 128), 256, 0, stream>>>(
            x, Wqkv + (size_t)l * Dd * 768, bqkv + l * 768, qkvb, M, Dd, 768, 0);
        attn_kernel<<<Bb * Hh * 2, 512, 0, stream>>>(
            qkvb, node_mask, offsets, elist, edge_index, edge_type, edge_weight, et_emb, attnout);
        gemm128<<<dim3(Dd / 128, M / 128), 256, 0, stream>>>(
            attnout, Wo + (size_t)l * Dd * Dd, bo + l * Dd, projb, M, Dd, Dd, 0);
        ln_kernel<<<M, 256, 0, stream>>>(x, projb, ln1_g + l * Dd, ln1_b + l * Dd);
        gemm128<<<dim3(FF / 128, M / 128), 256, 0, stream>>>(
            x, Wff1 + (size_t)l * Dd * FF, bff1 + l * FF, ffb, M, Dd, FF, 1);
        gemm128<<<dim3(Dd / 128, M / 128), 256, 0, stream>>>(
            ffb, Wff2 + (size_t)l * FF * Dd, bff2 + l * Dd, projb, M, FF, Dd, 0);
        ln_kernel<<<M, 256, 0, stream>>>(x, projb, ln2_g + l * Dd, ln2_b + l * Dd);
    }

    pool_kernel<<<dim3(16, Bb), 256, 0, stream>>>(x, text_mask, image_mask, pools);
    head_mlp<<<Bb, 256, 0, stream>>>(x, pools, gidx,
                                     Wm1, bm1, Wm2, bm2, Wm3, bm3, (float*)d_out);
}

// Round 5
// 1233.107 us; speedup vs baseline: 2.7527x; 1.2978x over previous
//
#include <hip/hip_runtime.h>
#include <hip/hip_bf16.h>
#include <math.h>

#define Bb 16
#define Nn 512
#define Dd 256
#define Hh 8
#define HD 32
#define Ll 3
#define INDIM 768
#define Ee 4096
#define FF 1024
#define KTP 516  // KT row pitch (pad 4): b128-aligned, 4-way staging conflict (cheap)

__device__ __forceinline__ float gelu_exact(float x) {
    return 0.5f * x * (1.0f + erff(x * 0.70710678118654752f));
}

// ---------------- edge bucketing ----------------

__global__ __launch_bounds__(256) void zero_kernel(int* __restrict__ p, int n) {
    int gid = blockIdx.x * 256 + threadIdx.x;
    if (gid < n) p[gid] = 0;
}

__global__ __launch_bounds__(256) void count_kernel(const int* __restrict__ edge_index,
                                                    int* __restrict__ counts) {
    int gid = blockIdx.x * 256 + threadIdx.x; // B*E = 65536
    int b = gid >> 12;
    int e = gid & (Ee - 1);
    int src = edge_index[b * 2 * Ee + e];
    atomicAdd(&counts[b * Nn + src], 1);
}

__global__ __launch_bounds__(1024) void scan_kernel(const int* __restrict__ counts,
                                                    int* __restrict__ offsets,
                                                    int* __restrict__ cursor) {
    __shared__ int ssum[1024];
    int t = threadIdx.x;
    int local[8];
    int s = 0;
#pragma unroll
    for (int i = 0; i < 8; i++) { local[i] = counts[t * 8 + i]; s += local[i]; }
    ssum[t] = s;
    __syncthreads();
    for (int off = 1; off < 1024; off *= 2) {
        __syncthreads();
        int v = (t >= off) ? ssum[t - off] : 0;
        __syncthreads();
        ssum[t] += v;
    }
    __syncthreads();
    int base = (t > 0) ? ssum[t - 1] : 0;
#pragma unroll
    for (int i = 0; i < 8; i++) {
        offsets[t * 8 + i] = base;
        cursor[t * 8 + i] = base;
        base += local[i];
    }
    if (t == 1023) offsets[8192] = base;
}

__global__ __launch_bounds__(256) void scatter_kernel(const int* __restrict__ edge_index,
                                                      int* __restrict__ cursor,
                                                      int* __restrict__ elist) {
    int gid = blockIdx.x * 256 + threadIdx.x;
    int b = gid >> 12;
    int e = gid & (Ee - 1);
    int src = edge_index[b * 2 * Ee + e];
    int pos = atomicAdd(&cursor[b * Nn + src], 1);
    elist[pos] = gid;
}

// ---------------- fp32 GEMM A: 128x128 tile, 8x8/thread, SW-pipelined ----------------

__global__ __launch_bounds__(256) void gemm128(const float* __restrict__ A,
                                               const float* __restrict__ W,
                                               const float* __restrict__ bias,
                                               float* __restrict__ C,
                                               int M, int K, int N, int act) {
    __shared__ float sA[16][128];  // [k][m]
    __shared__ float sB[16][128];  // [k][n]
    int t = threadIdx.x;
    int tx = t & 15, ty = t >> 4;
    int row0 = blockIdx.y * 128, col0 = blockIdx.x * 128;
    float acc[8][8] = {};
    int ar = t >> 1, ak = (t & 1) * 8;
    int bk = t >> 4, bc = (t & 15) * 8;

    const float* Ap = &A[(size_t)(row0 + ar) * K + ak];
    const float* Wp = &W[(size_t)bk * N + col0 + bc];

    // prologue: tile 0 into regs
    float4 a0 = *(const float4*)&Ap[0];
    float4 a1 = *(const float4*)&Ap[4];
    float4 b0 = *(const float4*)&Wp[0];
    float4 b1 = *(const float4*)&Wp[4];

    for (int k0 = 0; k0 < K; k0 += 16) {
        __syncthreads();  // previous tile's LDS reads complete
        sA[ak + 0][ar] = a0.x; sA[ak + 1][ar] = a0.y;
        sA[ak + 2][ar] = a0.z; sA[ak + 3][ar] = a0.w;
        sA[ak + 4][ar] = a1.x; sA[ak + 5][ar] = a1.y;
        sA[ak + 6][ar] = a1.z; sA[ak + 7][ar] = a1.w;
        *(float4*)&sB[bk][bc] = b0;
        *(float4*)&sB[bk][bc + 4] = b1;
        __syncthreads();
        // prefetch next tile (in flight during compute)
        if (k0 + 16 < K) {
            a0 = *(const float4*)&Ap[k0 + 16];
            a1 = *(const float4*)&Ap[k0 + 20];
            b0 = *(const float4*)&Wp[(size_t)(k0 + 16) * N];
            b1 = *(const float4*)&Wp[(size_t)(k0 + 16) * N + 4];
        }
#pragma unroll
        for (int kk = 0; kk < 16; kk++) {
            float4 av0 = *(const float4*)&sA[kk][ty * 4];
            float4 av1 = *(const float4*)&sA[kk][64 + ty * 4];
            float4 bv0 = *(const float4*)&sB[kk][tx * 4];
            float4 bv1 = *(const float4*)&sB[kk][64 + tx * 4];
            float a[8] = {av0.x, av0.y, av0.z, av0.w, av1.x, av1.y, av1.z, av1.w};
            float bb[8] = {bv0.x, bv0.y, bv0.z, bv0.w, bv1.x, bv1.y, bv1.z, bv1.w};
#pragma unroll
            for (int i = 0; i < 8; i++)
#pragma unroll
                for (int j = 0; j < 8; j++) acc[i][j] += a[i] * bb[j];
        }
    }
#pragma unroll
    for (int i = 0; i < 8; i++) {
        int r = row0 + ((i < 4) ? (ty * 4 + i) : (64 + ty * 4 + i - 4));
#pragma unroll
        for (int jh = 0; jh < 2; jh++) {
            int c0 = col0 + jh * 64 + tx * 4;
            float4 v;
            float* vv = (float*)&v;
#pragma unroll
            for (int j = 0; j < 4; j++) {
                float u = acc[i][jh * 4 + j] + bias[c0 + j];
                if (act == 1) u = gelu_exact(u);
                vv[j] = u;
            }
            *(float4*)&C[(size_t)r * N + c0] = v;
        }
    }
}

// ---------------- fp32 GEMM B: 128x64 tile, 8x4/thread (for N=256: 256 blocks) ----------------

__global__ __launch_bounds__(256) void gemm128x64(const float* __restrict__ A,
                                                  const float* __restrict__ W,
                                                  const float* __restrict__ bias,
                                                  float* __restrict__ C,
                                                  int M, int K, int N, int act) {
    __shared__ float sA[16][128];  // [k][m]
    __shared__ float sB[16][64];   // [k][n]
    int t = threadIdx.x;
    int tx = t & 15, ty = t >> 4;
    int row0 = blockIdx.y * 128, col0 = blockIdx.x * 64;
    float acc[8][4] = {};
    int ar = t >> 1, ak = (t & 1) * 8;
    int bk = t >> 4, bc = (t & 15) * 4;

    const float* Ap = &A[(size_t)(row0 + ar) * K + ak];
    const float* Wp = &W[(size_t)bk * N + col0 + bc];

    float4 a0 = *(const float4*)&Ap[0];
    float4 a1 = *(const float4*)&Ap[4];
    float4 b0 = *(const float4*)&Wp[0];

    for (int k0 = 0; k0 < K; k0 += 16) {
        __syncthreads();
        sA[ak + 0][ar] = a0.x; sA[ak + 1][ar] = a0.y;
        sA[ak + 2][ar] = a0.z; sA[ak + 3][ar] = a0.w;
        sA[ak + 4][ar] = a1.x; sA[ak + 5][ar] = a1.y;
        sA[ak + 6][ar] = a1.z; sA[ak + 7][ar] = a1.w;
        *(float4*)&sB[bk][bc] = b0;
        __syncthreads();
        if (k0 + 16 < K) {
            a0 = *(const float4*)&Ap[k0 + 16];
            a1 = *(const float4*)&Ap[k0 + 20];
            b0 = *(const float4*)&Wp[(size_t)(k0 + 16) * N];
        }
#pragma unroll
        for (int kk = 0; kk < 16; kk++) {
            float4 av0 = *(const float4*)&sA[kk][ty * 4];
            float4 av1 = *(const float4*)&sA[kk][64 + ty * 4];
            float4 bv = *(const float4*)&sB[kk][tx * 4];
            float a[8] = {av0.x, av0.y, av0.z, av0.w, av1.x, av1.y, av1.z, av1.w};
            float bb[4] = {bv.x, bv.y, bv.z, bv.w};
#pragma unroll
            for (int i = 0; i < 8; i++)
#pragma unroll
                for (int j = 0; j < 4; j++) acc[i][j] += a[i] * bb[j];
        }
    }
#pragma unroll
    for (int i = 0; i < 8; i++) {
        int r = row0 + ((i < 4) ? (ty * 4 + i) : (64 + ty * 4 + i - 4));
        int c0 = col0 + tx * 4;
        float4 v;
        float* vv = (float*)&v;
#pragma unroll
        for (int j = 0; j < 4; j++) {
            float u = acc[i][j] + bias[c0 + j];
            if (act == 1) u = gelu_exact(u);
            vv[j] = u;
        }
        *(float4*)&C[(size_t)r * N + c0] = v;
    }
}

// ---------------- attention v3: one block per (b,h,half), 512 threads ----------------

__global__ __launch_bounds__(512, 1) void attn_kernel(const float* __restrict__ qkv,
                                                      const int* __restrict__ node_mask,
                                                      const int* __restrict__ offsets,
                                                      const int* __restrict__ elist,
                                                      const int* __restrict__ edge_index,
                                                      const int* __restrict__ edge_type,
                                                      const float* __restrict__ edge_weight,
                                                      const float* __restrict__ et_emb,
                                                      float* __restrict__ outbuf) {
    int bid = blockIdx.x;          // b*16 + h*2 + half
    int half = bid & 1;
    int h = (bid >> 1) & 7;
    int b = bid >> 4;
    int t = threadIdx.x;
    int w = t >> 6;   // wave 0..7
    int L = t & 63;   // lane

    __shared__ __align__(16) float KT[HD][KTP];
    __shared__ __align__(16) float srow[8][4][Nn];
    __shared__ __align__(16) float maskb[Nn];
    __shared__ float qtile[8][4][HD];
    __shared__ float etl[4];

    for (int i = t; i < Nn * HD; i += 512) {
        int m = i >> 5, d = i & 31;
        KT[d][m] = qkv[(size_t)(b * Nn + m) * 768 + 256 + h * HD + d];
    }
    if (t < Nn) maskb[t] = node_mask[b * Nn + t] ? 0.0f : -INFINITY;
    if (t < 4) etl[t] = et_emb[t * Hh + h];
    __syncthreads();

    const float scale = 0.17677669529663687f;
    int base = half * 256;
    int m8 = 8 * L;

    float4 mb0 = *(const float4*)&maskb[m8];
    float4 mb1 = *(const float4*)&maskb[m8 + 4];
    float mb[8] = {mb0.x, mb0.y, mb0.z, mb0.w, mb1.x, mb1.y, mb1.z, mb1.w};

    for (int g = 0; g < 8; g++) {
        int n0 = base + w * 32 + g * 4;

        for (int i = L; i < 4 * HD; i += 64) {
            int r = i >> 5, d = i & 31;
            qtile[w][r][d] = qkv[(size_t)(b * Nn + n0 + r) * 768 + h * HD + d] * scale;
        }
        asm volatile("s_waitcnt lgkmcnt(0) vmcnt(0)" ::: "memory");

        float acc[4][8];
#pragma unroll
        for (int r = 0; r < 4; r++)
#pragma unroll
            for (int j = 0; j < 8; j++) acc[r][j] = 0.0f;
#pragma unroll 4
        for (int d = 0; d < HD; d++) {
            float4 k0 = *(const float4*)&KT[d][m8];
            float4 k1 = *(const float4*)&KT[d][m8 + 4];
            float kk[8] = {k0.x, k0.y, k0.z, k0.w, k1.x, k1.y, k1.z, k1.w};
            float q0 = qtile[w][0][d], q1 = qtile[w][1][d];
            float q2 = qtile[w][2][d], q3 = qtile[w][3][d];
#pragma unroll
            for (int j = 0; j < 8; j++) {
                acc[0][j] += q0 * kk[j];
                acc[1][j] += q1 * kk[j];
                acc[2][j] += q2 * kk[j];
                acc[3][j] += q3 * kk[j];
            }
        }

#pragma unroll
        for (int r = 0; r < 4; r++) {
            *(float4*)&srow[w][r][m8] = make_float4(acc[r][0], acc[r][1], acc[r][2], acc[r][3]);
            *(float4*)&srow[w][r][m8 + 4] = make_float4(acc[r][4], acc[r][5], acc[r][6], acc[r][7]);
        }
        asm volatile("s_waitcnt lgkmcnt(0)" ::: "memory");

        int beg = offsets[b * Nn + n0];
        int end = offsets[b * Nn + n0 + 4];
        for (int i = beg + L; i < end; i += 64) {
            int ge = elist[i];
            int e = ge & (Ee - 1);
            int src = edge_index[b * 2 * Ee + e];
            int dst = edge_index[b * 2 * Ee + Ee + e];
            int ty = edge_type[b * Ee + e];
            float wgt = edge_weight[b * Ee + e];
            float val = etl[ty] + (ty == 2 ? wgt : 0.0f);
            atomicAdd(&srow[w][src - n0][dst], val);
        }
        asm volatile("s_waitcnt lgkmcnt(0)" ::: "memory");

        float inv[4];
#pragma unroll
        for (int r = 0; r < 4; r++) {
            float4 s0 = *(const float4*)&srow[w][r][m8];
            float4 s1 = *(const float4*)&srow[w][r][m8 + 4];
            float s[8] = {s0.x, s0.y, s0.z, s0.w, s1.x, s1.y, s1.z, s1.w};
#pragma unroll
            for (int j = 0; j < 8; j++) s[j] += mb[j];
            float mx = s[0];
#pragma unroll
            for (int j = 1; j < 8; j++) mx = fmaxf(mx, s[j]);
#pragma unroll
            for (int o = 1; o < 64; o <<= 1) mx = fmaxf(mx, __shfl_xor(mx, o));
            float sum = 0.0f;
#pragma unroll
            for (int j = 0; j < 8; j++) {
                s[j] = __expf(s[j] - mx);
                sum += s[j];
            }
#pragma unroll
            for (int o = 1; o < 64; o <<= 1) sum += __shfl_xor(sum, o);
            inv[r] = 1.0f / sum;
            *(float4*)&srow[w][r][m8] = make_float4(s[0], s[1], s[2], s[3]);
            *(float4*)&srow[w][r][m8 + 4] = make_float4(s[4], s[5], s[6], s[7]);
        }
        asm volatile("s_waitcnt lgkmcnt(0)" ::: "memory");

        int d = L & 31, h2 = L >> 5;
        int mbase = h2 * 256;
        const float* vp = qkv + (size_t)(b * Nn + mbase) * 768 + 512 + h * HD + d;
        float o0 = 0.0f, o1 = 0.0f, o2 = 0.0f, o3 = 0.0f;
#pragma unroll 4
        for (int mc = 0; mc < 256; mc += 4) {
            float v0 = vp[(size_t)(mc + 0) * 768];
            float v1 = vp[(size_t)(mc + 1) * 768];
            float v2 = vp[(size_t)(mc + 2) * 768];
            float v3 = vp[(size_t)(mc + 3) * 768];
            float4 s0 = *(const float4*)&srow[w][0][mbase + mc];
            float4 s1 = *(const float4*)&srow[w][1][mbase + mc];
            float4 s2 = *(const float4*)&srow[w][2][mbase + mc];
            float4 s3 = *(const float4*)&srow[w][3][mbase + mc];
            o0 += s0.x * v0 + s0.y * v1 + s0.z * v2 + s0.w * v3;
            o1 += s1.x * v0 + s1.y * v1 + s1.z * v2 + s1.w * v3;
            o2 += s2.x * v0 + s2.y * v1 + s2.z * v2 + s2.w * v3;
            o3 += s3.x * v0 + s3.y * v1 + s3.z * v2 + s3.w * v3;
        }
        o0 += __shfl_xor(o0, 32);
        o1 += __shfl_xor(o1, 32);
        o2 += __shfl_xor(o2, 32);
        o3 += __shfl_xor(o3, 32);
        if (h2 == 0) {
            outbuf[(size_t)(b * Nn + n0 + 0) * Dd + h * HD + d] = o0 * inv[0];
            outbuf[(size_t)(b * Nn + n0 + 1) * Dd + h * HD + d] = o1 * inv[1];
            outbuf[(size_t)(b * Nn + n0 + 2) * Dd + h * HD + d] = o2 * inv[2];
            outbuf[(size_t)(b * Nn + n0 + 3) * Dd + h * HD + d] = o3 * inv[3];
        }
    }
}

// ---------------- residual + LayerNorm ----------------

__global__ __launch_bounds__(256) void ln_kernel(float* __restrict__ x,
                                                 const float* __restrict__ res,
                                                 const float* __restrict__ g,
                                                 const float* __restrict__ bta) {
    int row = blockIdx.x;
    int t = threadIdx.x;
    __shared__ float red[4];
    __shared__ float stats[2];
    size_t idx = (size_t)row * Dd + t;
    float v = x[idx] + res[idx];
    float sm = v;
    for (int o = 32; o > 0; o >>= 1) sm += __shfl_down(sm, o);
    if ((t & 63) == 0) red[t >> 6] = sm;
    __syncthreads();
    if (t == 0) stats[0] = (red[0] + red[1] + red[2] + red[3]) * (1.0f / Dd);
    __syncthreads();
    float mu = stats[0];
    float dv = v - mu;
    float s2 = dv * dv;
    for (int o = 32; o > 0; o >>= 1) s2 += __shfl_down(s2, o);
    if ((t & 63) == 0) red[t >> 6] = s2;
    __syncthreads();
    if (t == 0) stats[1] = 1.0f / sqrtf((red[0] + red[1] + red[2] + red[3]) * (1.0f / Dd) + 1e-5f);
    __syncthreads();
    x[idx] = dv * stats[1] * g[t] + bta[t];
}

// ---------------- head ----------------
// pools per b (stride 514): [0..255]=text sum, [256..511]=image sum, [512]=tc, [513]=ic
// comb per b (stride 776): [0..768] = [global_embed | text_pool | image_pool | conflict]

__global__ __launch_bounds__(256) void pool_kernel(const float* __restrict__ x,
                                                   const int* __restrict__ text_mask,
                                                   const int* __restrict__ image_mask,
                                                   float* __restrict__ pools) {
    int b = blockIdx.y;
    int n0 = blockIdx.x * 32;
    int t = threadIdx.x;
    float tp = 0.0f, ip = 0.0f, c1 = 0.0f, c2 = 0.0f;
    for (int n = n0; n < n0 + 32; n++) {
        float xv = x[(size_t)(b * Nn + n) * Dd + t];
        int tm = text_mask[b * Nn + n];
        int im = image_mask[b * Nn + n];
        tp += tm ? xv : 0.0f;
        ip += im ? xv : 0.0f;
        c1 += (float)tm;
        c2 += (float)im;
    }
    atomicAdd(&pools[b * 514 + t], tp);
    atomicAdd(&pools[b * 514 + 256 + t], ip);
    if (t == 0) {
        atomicAdd(&pools[b * 514 + 512], c1);
        atomicAdd(&pools[b * 514 + 513], c2);
    }
}

__global__ __launch_bounds__(256) void comb_kernel(const float* __restrict__ x,
                                                   const float* __restrict__ pools,
                                                   const int* __restrict__ gidx,
                                                   float* __restrict__ comb) {
    int b = blockIdx.x;
    int t = threadIdx.x;
    __shared__ float redd[12];
    float tc = fmaxf(pools[b * 514 + 512], 1.0f);
    float ic = fmaxf(pools[b * 514 + 513], 1.0f);
    float tp = pools[b * 514 + t] / tc;
    float ip = pools[b * 514 + 256 + t] / ic;
    int gi = gidx[b];
    comb[b * 776 + t] = x[(size_t)(b * Nn + gi) * Dd + t];
    comb[b * 776 + 256 + t] = tp;
    comb[b * 776 + 512 + t] = ip;
    float dotv = tp * ip, n1v = tp * tp, n2v = ip * ip;
    for (int o = 32; o > 0; o >>= 1) {
        dotv += __shfl_down(dotv, o);
        n1v += __shfl_down(n1v, o);
        n2v += __shfl_down(n2v, o);
    }
    if ((t & 63) == 0) { redd[t >> 6] = dotv; redd[4 + (t >> 6)] = n1v; redd[8 + (t >> 6)] = n2v; }
    __syncthreads();
    if (t == 0) {
        float dd = redd[0] + redd[1] + redd[2] + redd[3];
        float a1 = fmaxf(sqrtf(redd[4] + redd[5] + redd[6] + redd[7]), 1e-6f);
        float a2 = fmaxf(sqrtf(redd[8] + redd[9] + redd[10] + redd[11]), 1e-6f);
        comb[b * 776 + 768] = 1.0f - dd / (a1 * a2);
    }
}

// h1 = gelu(comb @ Wm1 + bm1): grid (4 j-chunks, 16 b), k split in 2 halves/thread
__global__ __launch_bounds__(256) void h1_kernel(const float* __restrict__ comb,
                                                 const float* __restrict__ Wm1,
                                                 const float* __restrict__ bm1,
                                                 float* __restrict__ h1) {
    int b = blockIdx.y;
    int jc = blockIdx.x;
    int t = threadIdx.x;
    __shared__ float scomb[776];
    __shared__ float partial[2][128];
    for (int i = t; i < 769; i += 256) scomb[i] = comb[b * 776 + i];
    __syncthreads();
    int j = jc * 128 + (t & 127);
    int kh = t >> 7;
    int kbeg = kh ? 384 : 0;
    int kend = kh ? 769 : 384;
    float acc = 0.0f;
#pragma unroll 8
    for (int k = kbeg; k < kend; k++) acc += scomb[k] * Wm1[k * 512 + j];
    partial[kh][t & 127] = acc;
    __syncthreads();
    if (t < 128) {
        float v = partial[0][t] + partial[1][t] + bm1[jc * 128 + t];
        h1[b * 512 + jc * 128 + t] = gelu_exact(v);
    }
}

// h2 = gelu(h1 @ Wm2 + bm2); logits = h2 @ Wm3 + bm3
__global__ __launch_bounds__(256) void head_fin(const float* __restrict__ h1,
                                                const float* __restrict__ Wm2,
                                                const float* __restrict__ bm2,
                                                const float* __restrict__ Wm3,
                                                const float* __restrict__ bm3,
                                                float* __restrict__ out) {
    int b = blockIdx.x;
    int t = threadIdx.x;
    __shared__ float h1s[512];
    __shared__ float red[4];
    for (int i = t; i < 512; i += 256) h1s[i] = h1[b * 512 + i];
    __syncthreads();
    float acc = bm2[t];
#pragma unroll 8
    for (int k = 0; k < 512; k++) acc += h1s[k] * Wm2[k * 256 + t];
    float h2 = gelu_exact(acc);
    float lv = h2 * Wm3[t];
    for (int o = 32; o > 0; o >>= 1) lv += __shfl_down(lv, o);
    if ((t & 63) == 0) red[t >> 6] = lv;
    __syncthreads();
    if (t == 0) out[b] = red[0] + red[1] + red[2] + red[3] + bm3[0];
}

// ---------------- launch ----------------

extern "C" void kernel_launch(void* const* d_in, const int* in_sizes, int n_in,
                              void* d_out, int out_size, void* d_ws, size_t ws_size,
                              hipStream_t stream) {
    const float* node_feats = (const float*)d_in[0];
    const int* node_mask = (const int*)d_in[1];
    const int* text_mask = (const int*)d_in[2];
    const int* image_mask = (const int*)d_in[3];
    const int* gidx = (const int*)d_in[4];
    const int* edge_index = (const int*)d_in[5];
    const int* edge_type = (const int*)d_in[6];
    const float* edge_weight = (const float*)d_in[7];
    const float* W_in = (const float*)d_in[8];
    const float* b_in = (const float*)d_in[9];
    const float* Wqkv = (const float*)d_in[10];
    const float* bqkv = (const float*)d_in[11];
    const float* Wo = (const float*)d_in[12];
    const float* bo = (const float*)d_in[13];
    const float* ln1_g = (const float*)d_in[14];
    const float* ln1_b = (const float*)d_in[15];
    const float* ln2_g = (const float*)d_in[16];
    const float* ln2_b = (const float*)d_in[17];
    const float* Wff1 = (const float*)d_in[18];
    const float* bff1 = (const float*)d_in[19];
    const float* Wff2 = (const float*)d_in[20];
    const float* bff2 = (const float*)d_in[21];
    const float* et_emb = (const float*)d_in[22];
    const float* Wm1 = (const float*)d_in[23];
    const float* bm1 = (const float*)d_in[24];
    const float* Wm2 = (const float*)d_in[25];
    const float* bm2 = (const float*)d_in[26];
    const float* Wm3 = (const float*)d_in[27];
    const float* bm3 = (const float*)d_in[28];

    const int M = Bb * Nn; // 8192
    char* ws = (char*)d_ws;
    size_t off = 0;
    auto alloc = [&](size_t bytes) {
        void* p = ws + off;
        off += (bytes + 255) & ~(size_t)255;
        return p;
    };
    float* x = (float*)alloc((size_t)M * Dd * 4);        // 8 MB
    float* qkvb = (float*)alloc((size_t)M * FF * 4);     // 32 MB union (qkv 24MB / ff 32MB)
    float* ffb = qkvb;
    float* attnout = (float*)alloc((size_t)M * Dd * 4);  // 8 MB
    float* projb = (float*)alloc((size_t)M * Dd * 4);    // 8 MB
    int* counts = (int*)alloc(8192 * 4);
    int* offsets = (int*)alloc(8193 * 4);
    int* cursor = (int*)alloc(8192 * 4);
    int* elist = (int*)alloc((size_t)Bb * Ee * 4);
    float* pools = (float*)alloc((size_t)Bb * 514 * 4);
    float* comb = (float*)alloc((size_t)Bb * 776 * 4);
    float* h1 = (float*)alloc((size_t)Bb * 512 * 4);
    (void)ws_size;

    zero_kernel<<<32, 256, 0, stream>>>(counts, 8192);
    zero_kernel<<<(Bb * 514 + 255) / 256, 256, 0, stream>>>((int*)pools, Bb * 514);
    count_kernel<<<256, 256, 0, stream>>>(edge_index, counts);
    scan_kernel<<<1, 1024, 0, stream>>>(counts, offsets, cursor);
    scatter_kernel<<<256, 256, 0, stream>>>(edge_index, cursor, elist);

    // input proj: N=256 -> 128x64 tiles (256 blocks)
    gemm128x64<<<dim3(Dd / 64, M / 128), 256, 0, stream>>>(node_feats, W_in, b_in, x, M, INDIM, Dd, 0);

    for (int l = 0; l < Ll; l++) {
        gemm128<<<dim3(768 / 128, M / 128), 256, 0, stream>>>(
            x, Wqkv + (size_t)l * Dd * 768, bqkv + l * 768, qkvb, M, Dd, 768, 0);
        attn_kernel<<<Bb * Hh * 2, 512, 0, stream>>>(
            qkvb, node_mask, offsets, elist, edge_index, edge_type, edge_weight, et_emb, attnout);
        gemm128x64<<<dim3(Dd / 64, M / 128), 256, 0, stream>>>(
            attnout, Wo + (size_t)l * Dd * Dd, bo + l * Dd, projb, M, Dd, Dd, 0);
        ln_kernel<<<M, 256, 0, stream>>>(x, projb, ln1_g + l * Dd, ln1_b + l * Dd);
        gemm128<<<dim3(FF / 128, M / 128), 256, 0, stream>>>(
            x, Wff1 + (size_t)l * Dd * FF, bff1 + l * FF, ffb, M, Dd, FF, 1);
        gemm128x64<<<dim3(Dd / 64, M / 128), 256, 0, stream>>>(
            ffb, Wff2 + (size_t)l * FF * Dd, bff2 + l * Dd, projb, M, FF, Dd, 0);
        ln_kernel<<<M, 256, 0, stream>>>(x, projb, ln2_g + l * Dd, ln2_b + l * Dd);
    }

    pool_kernel<<<dim3(16, Bb), 256, 0, stream>>>(x, text_mask, image_mask, pools);
    comb_kernel<<<Bb, 256, 0, stream>>>(x, pools, gidx, comb);
    h1_kernel<<<dim3(4, Bb), 256, 0, stream>>>(comb, Wm1, bm1, h1);
    head_fin<<<Bb, 256, 0, stream>>>(h1, Wm2, bm2, Wm3, bm3, (float*)d_out);
}